// Round 4
// baseline (163.851 us; speedup 1.0000x reference)
//
#include <hip/hip_runtime.h>
#include <hip/hip_bf16.h>
#include <stdint.h>

#define Bdim 32
#define Tdim 128
#define Fdim 2048
#define Mdim (Bdim*Tdim)   // 4096

#define BM 128
#define BN 128
#define BK 32

typedef __attribute__((ext_vector_type(8))) short bf16x8;
typedef __attribute__((ext_vector_type(4))) float f32x4;

__device__ inline unsigned short f2bf(float f) {
    union { float f; unsigned u; } x; x.f = f;
    unsigned r = (x.u + 0x7fffu + ((x.u >> 16) & 1u)) >> 16;   // RNE
    return (unsigned short)r;
}

// ---------------- kernel 1: fp32 -> bf16 convert (input and W) ----------------
__global__ void convert_kernel(const float* __restrict__ A, const float* __restrict__ W,
                               unsigned short* __restrict__ a16, unsigned short* __restrict__ w16) {
    const int nA4 = (Mdim * Fdim) / 4;   // 2097152
    const int nW4 = (Fdim * Fdim) / 4;   // 1048576
    const int stride = gridDim.x * blockDim.x;
    for (int i = blockIdx.x * blockDim.x + threadIdx.x; i < nA4 + nW4; i += stride) {
        const float4* src; unsigned short* dst; int j;
        if (i < nA4) { src = (const float4*)A; dst = a16; j = i; }
        else         { src = (const float4*)W; dst = w16; j = i - nA4; }
        float4 v = src[j];
        ushort4 o;
        o.x = f2bf(v.x); o.y = f2bf(v.y); o.z = f2bf(v.z); o.w = f2bf(v.w);
        *(ushort4*)(dst + 4 * (size_t)j) = o;
    }
}

// ---------------- kernel 2: bf16 MFMA GEMM (m97 structure) ----------------
// C[M,N] = A[M,K] * W[N,K]^T   (both K-major), C fp32
__global__ __launch_bounds__(256) void gemm_kernel(const unsigned short* __restrict__ A,
                                                   const unsigned short* __restrict__ Wm,
                                                   float* __restrict__ C) {
    __shared__ __align__(16) unsigned short sA[BM * BK];   // [128][32] bf16, 8 KB
    __shared__ __align__(16) unsigned short sB[BN * BK];

    const int tid = threadIdx.x;
    const int wid = tid >> 6, lane = tid & 63;
    const int wr = wid >> 1, wc = wid & 1;          // wave -> 64x64 quadrant
    const int m0 = blockIdx.y * BM, n0 = blockIdx.x * BN;

    f32x4 acc[4][4];
#pragma unroll
    for (int i = 0; i < 4; i++)
#pragma unroll
        for (int j = 0; j < 4; j++) acc[i][j] = f32x4{0.f, 0.f, 0.f, 0.f};

    const int off0 = wid * 2048 + lane * 16;        // byte offset in 8192B tile
    const int frow = lane & 15, fk = (lane >> 4) * 8;

    for (int kt = 0; kt < Fdim / BK; ++kt) {
        const int k0 = kt * BK;
        // stage A,B tiles: per wave 2 chunks of 1024B each per tile
#pragma unroll
        for (int j = 0; j < 2; ++j) {
            const int off  = off0 + j * 1024;
            const int row  = off >> 6;      // 64 bytes per tile row
            const int cole = (off & 63) >> 1;
            const unsigned short* ga = A  + (size_t)(m0 + row) * Fdim + k0 + cole;
            const unsigned short* gb = Wm + (size_t)(n0 + row) * Fdim + k0 + cole;
            __builtin_amdgcn_global_load_lds(
                (const __attribute__((address_space(1))) void*)ga,
                (__attribute__((address_space(3))) void*)(sA + (wid * 2048 + j * 1024) / 2),
                16, 0, 0);
            __builtin_amdgcn_global_load_lds(
                (const __attribute__((address_space(1))) void*)gb,
                (__attribute__((address_space(3))) void*)(sB + (wid * 2048 + j * 1024) / 2),
                16, 0, 0);
        }
        __syncthreads();

        bf16x8 af[4], bfr[4];
#pragma unroll
        for (int mi = 0; mi < 4; mi++)
            af[mi] = *(const bf16x8*)(sA + (wr * 64 + mi * 16 + frow) * BK + fk);
#pragma unroll
        for (int ni = 0; ni < 4; ni++)
            bfr[ni] = *(const bf16x8*)(sB + (wc * 64 + ni * 16 + frow) * BK + fk);
#pragma unroll
        for (int mi = 0; mi < 4; mi++)
#pragma unroll
            for (int ni = 0; ni < 4; ni++)
                acc[mi][ni] = __builtin_amdgcn_mfma_f32_16x16x32_bf16(af[mi], bfr[ni], acc[mi][ni], 0, 0, 0);
        __syncthreads();
    }

    // epilogue: verified C/D mapping col=lane&15, row=(lane>>4)*4+r
    const int crow = m0 + wr * 64 + (lane >> 4) * 4;
    const int ccol = n0 + wc * 64 + (lane & 15);
#pragma unroll
    for (int mi = 0; mi < 4; mi++)
#pragma unroll
        for (int ni = 0; ni < 4; ni++) {
            float* cp = C + (size_t)(crow + mi * 16) * Fdim + ccol + ni * 16;
#pragma unroll
            for (int r = 0; r < 4; r++) cp[(size_t)r * Fdim] = acc[mi][ni][r];
        }
}

// ---------------- fallback fp32 GEMM (only if ws too small; insurance) ----------------
__global__ void gemm_f32_naive(const float* __restrict__ A, const float* __restrict__ W,
                               float* __restrict__ C) {
    int col = blockIdx.x * blockDim.x + threadIdx.x;
    int row = blockIdx.y;
    float s = 0.f;
    for (int k = 0; k < Fdim; k++) s += A[(size_t)row * Fdim + k] * W[(size_t)col * Fdim + k];
    C[(size_t)row * Fdim + col] = s;
}

// ---------------- kernel 3: LIF scan, in-place on gs (=d_out) ----------------
__global__ void lif_kernel(float* __restrict__ gs, const float* __restrict__ bias) {
    int idx = blockIdx.x * blockDim.x + threadIdx.x;   // b*F + f
    int b = idx >> 11, f = idx & (Fdim - 1);
    const float bf = bias[f];
    float* p = gs + (size_t)b * Tdim * Fdim + f;
    float v = 0.f;
#pragma unroll
    for (int t0 = 0; t0 < Tdim; t0 += 8) {
        float g[8];
#pragma unroll
        for (int j = 0; j < 8; j++) g[j] = p[(size_t)(t0 + j) * Fdim];
#pragma unroll
        for (int j = 0; j < 8; j++) {
            float vn = v + 0.01f * ((0.0f - v) + (g[j] + bf));
            float z = (vn > 1.0f) ? 1.0f : 0.0f;
            v = vn - z;                    // subtractive reset (V_TH = 1)
            p[(size_t)(t0 + j) * Fdim] = z;
        }
    }
}

extern "C" void kernel_launch(void* const* d_in, const int* in_sizes, int n_in,
                              void* d_out, int out_size, void* d_ws, size_t ws_size,
                              hipStream_t stream) {
    const float* inp  = (const float*)d_in[0];
    const float* W    = (const float*)d_in[1];
    const float* bias = (const float*)d_in[2];
    float* out = (float*)d_out;

    const size_t needA = (size_t)Mdim * Fdim * 2;   // 16.8 MB
    const size_t needW = (size_t)Fdim * Fdim * 2;   //  8.4 MB

    if (ws_size >= needA + needW) {
        unsigned short* a16 = (unsigned short*)d_ws;
        unsigned short* w16 = (unsigned short*)((char*)d_ws + needA);
        convert_kernel<<<2048, 256, 0, stream>>>(inp, W, a16, w16);
        dim3 grid(Fdim / BN, Mdim / BM);            // (16, 32) = 512 blocks
        gemm_kernel<<<grid, 256, 0, stream>>>(a16, w16, out);
    } else {
        dim3 grid(Fdim / 256, Mdim);
        gemm_f32_naive<<<grid, 256, 0, stream>>>(inp, W, out);
    }
    lif_kernel<<<(Bdim * Fdim) / 256, 256, 0, stream>>>(out, bias);
}